// Round 1
// baseline (267.809 us; speedup 1.0000x reference)
//
#include <hip/hip_runtime.h>
#include <math.h>

namespace {
constexpr int S_N   = 4096;
constexpr int D_N   = 128;
constexpr int DD_N  = 64;
constexpr int REL_N = 8;
constexpr int R_N   = 512;
constexpr int NTOT  = S_N * REL_N;                        // 32768
constexpr int ROWLEN = R_N + NTOT;                        // 33280
constexpr long long FC_IN_N = (long long)DD_N * ROWLEN;   // 2,129,920
constexpr int CHUNK = 1024;                               // floats per k_mv block
constexpr int NBLK_MV = (int)(FC_IN_N / CHUNK);           // 2080 (exact)
}

// h[dd*ROWLEN + c] = rule_features[dd*512 + c]   (c < 512)
__global__ __launch_bounds__(256) void k_rules(const float* __restrict__ rf,
                                               float* __restrict__ h) {
    int i  = blockIdx.x * 256 + threadIdx.x;   // float4 id, 8192 total
    int dd = i >> 7;                           // 128 float4 per rf row
    int c4 = i & 127;
    float4 v = reinterpret_cast<const float4*>(rf)[i];
    reinterpret_cast<float4*>(h)[(size_t)dd * (ROWLEN / 4) + c4] = v;
}

// kg[dd][n] = (dise[dd] . x[n]) / (||dise[dd]|| * ||x[n]||),  x[n] = mask[s]*(embed[s]+rel[r])
// written to h[dd*ROWLEN + 512 + n],  n = s*8 + r
__global__ __launch_bounds__(256) void k_kg(const int* __restrict__ inputs,
                                            const float* __restrict__ embed,
                                            const float* __restrict__ rel,
                                            const float* __restrict__ dise,
                                            float* __restrict__ h) {
    __shared__ __align__(16) float buf[64 * 129];  // dise staging (pad 129), then x tile [64][128]
    __shared__ float xsc[64];
    const int tid  = threadIdx.x;
    const int lane = tid & 63;
    const int wave = tid >> 6;
    const int n0   = blockIdx.x * 64;

    // 1) stage dise rows into LDS, pad-129 so per-row readout is 2-way (free)
    for (int i = tid; i < DD_N * D_N; i += 256) {
        buf[(i >> 7) * 129 + (i & 127)] = dise[i];
    }
    __syncthreads();

    // 2) my dise row (lane = dd) -> registers; dsc = 1/||dise[lane]||
    float dw[D_N];
    float dsq = 0.f;
    #pragma unroll
    for (int e = 0; e < D_N; ++e) {
        dw[e] = buf[lane * 129 + e];
        dsq += dw[e] * dw[e];
    }
    const float dsc = rsqrtf(dsq);
    __syncthreads();   // everyone done reading dise before buf is reused

    // 3) stage raw masked x tile into buf[0..8191]; per-row inverse norm in xsc
    {
        const int nl = tid >> 2, p = tid & 3;   // 4 threads per n-row, 32 elems each
        const int n = n0 + nl;
        const int s = n >> 3, r = n & 7;
        const float m = (inputs[s] != 0) ? 1.0f : 0.0f;
        const float4* es = reinterpret_cast<const float4*>(embed + (size_t)s * D_N);
        const float4* rs = reinterpret_cast<const float4*>(rel + (size_t)r * D_N);
        float4* xr = reinterpret_cast<float4*>(&buf[nl * D_N]);
        float sq = 0.f;
        #pragma unroll
        for (int i = 0; i < 8; ++i) {
            float4 a = es[p * 8 + i];
            float4 b = rs[p * 8 + i];
            float4 x;
            x.x = m * (a.x + b.x);
            x.y = m * (a.y + b.y);
            x.z = m * (a.z + b.z);
            x.w = m * (a.w + b.w);
            sq += x.x * x.x + x.y * x.y + x.z * x.z + x.w * x.w;
            xr[p * 8 + i] = x;
        }
        sq += __shfl_xor(sq, 1);   // 4-lane group shares one n-row
        sq += __shfl_xor(sq, 2);
        if (p == 0) xsc[nl] = (sq > 0.f) ? rsqrtf(sq) : 0.f;
    }
    __syncthreads();

    // 4) dots: lane = dd; this wave handles n-locals [wave*16, wave*16+16)
    //    x reads are all-lane-broadcast (conflict-free); dise comes from registers.
    float acc[16];
    #pragma unroll
    for (int j = 0; j < 16; ++j) {
        const int nl = wave * 16 + j;
        const float4* xr = reinterpret_cast<const float4*>(&buf[nl * D_N]);
        float a0 = 0.f, a1 = 0.f, a2 = 0.f, a3 = 0.f;
        #pragma unroll
        for (int i = 0; i < 32; i += 4) {
            float4 x0 = xr[i], x1 = xr[i + 1], x2 = xr[i + 2], x3 = xr[i + 3];
            a0 += dw[4*i+ 0]*x0.x + dw[4*i+ 1]*x0.y + dw[4*i+ 2]*x0.z + dw[4*i+ 3]*x0.w;
            a1 += dw[4*i+ 4]*x1.x + dw[4*i+ 5]*x1.y + dw[4*i+ 6]*x1.z + dw[4*i+ 7]*x1.w;
            a2 += dw[4*i+ 8]*x2.x + dw[4*i+ 9]*x2.y + dw[4*i+10]*x2.z + dw[4*i+11]*x2.w;
            a3 += dw[4*i+12]*x3.x + dw[4*i+13]*x3.y + dw[4*i+14]*x3.z + dw[4*i+15]*x3.w;
        }
        acc[j] = (a0 + a1 + a2 + a3) * dsc * xsc[nl];
    }

    // 5) write 16 consecutive kg values for my dd row (16B-aligned float4 stores)
    float* dst = h + (size_t)lane * ROWLEN + R_N + n0 + wave * 16;
    #pragma unroll
    for (int j = 0; j < 16; j += 4) {
        float4 o;
        o.x = acc[j]; o.y = acc[j + 1]; o.z = acc[j + 2]; o.w = acc[j + 3];
        *reinterpret_cast<float4*>(dst + j) = o;
    }
}

// out_part[block][k] = sum over this block's 1024-column chunk of h[c]*fc_w[k][c]
__global__ __launch_bounds__(256) void k_mv(const float* __restrict__ fcw,
                                            const float* __restrict__ h,
                                            float* __restrict__ partials) {
    const int tid  = threadIdx.x;
    const int lane = tid & 63;
    const int wave = tid >> 6;
    const size_t cbase = (size_t)blockIdx.x * CHUNK;

    const float4* hp = reinterpret_cast<const float4*>(h + cbase);
    float4 h0 = hp[lane], h1 = hp[lane + 64], h2 = hp[lane + 128], h3 = hp[lane + 192];

    float acc[16];
    #pragma unroll
    for (int j = 0; j < 16; ++j) {
        const int k = wave * 16 + j;   // wave owns 16 output rows
        const float4* wp = reinterpret_cast<const float4*>(fcw + (size_t)k * FC_IN_N + cbase);
        float4 w0 = wp[lane], w1 = wp[lane + 64], w2 = wp[lane + 128], w3 = wp[lane + 192];
        float a;
        a  = w0.x*h0.x + w0.y*h0.y + w0.z*h0.z + w0.w*h0.w;
        a += w1.x*h1.x + w1.y*h1.y + w1.z*h1.z + w1.w*h1.w;
        a += w2.x*h2.x + w2.y*h2.y + w2.z*h2.z + w2.w*h2.w;
        a += w3.x*h3.x + w3.y*h3.y + w3.z*h3.z + w3.w*h3.w;
        #pragma unroll
        for (int m = 32; m >= 1; m >>= 1) a += __shfl_xor(a, m);
        acc[j] = a;
    }

    __shared__ float red[64];
    if (lane == 0) {
        #pragma unroll
        for (int j = 0; j < 16; ++j) red[wave * 16 + j] = acc[j];
    }
    __syncthreads();
    if (tid < 64) partials[(size_t)blockIdx.x * 64 + tid] = red[tid];
}

// out[k] = sigmoid(fc_b[k] + sum_b partials[b][k])
__global__ __launch_bounds__(256) void k_fin(const float* __restrict__ partials,
                                             const float* __restrict__ fcb,
                                             float* __restrict__ out) {
    const int tid = threadIdx.x;
    const int k = tid & 63, g = tid >> 6;
    float s = 0.f;
    for (int b = g; b < NBLK_MV; b += 4) s += partials[(size_t)b * 64 + k];
    __shared__ float red[4][64];
    red[g][k] = s;
    __syncthreads();
    if (tid < 64) {
        float t = red[0][tid] + red[1][tid] + red[2][tid] + red[3][tid] + fcb[tid];
        out[tid] = 1.0f / (1.0f + expf(-t));
    }
}

extern "C" void kernel_launch(void* const* d_in, const int* in_sizes, int n_in,
                              void* d_out, int out_size, void* d_ws, size_t ws_size,
                              hipStream_t stream) {
    const int*   inputs = (const int*)  d_in[0];
    const float* rf     = (const float*)d_in[1];
    const float* embed  = (const float*)d_in[2];
    const float* rel    = (const float*)d_in[3];
    const float* dise   = (const float*)d_in[4];
    const float* fcw    = (const float*)d_in[5];
    const float* fcb    = (const float*)d_in[6];
    float* out = (float*)d_out;

    // ws layout: h [FC_IN] floats, then partials [NBLK_MV*64] floats (~8.7 MB total)
    float* ws = (float*)d_ws;
    float* h        = ws;
    float* partials = ws + FC_IN_N;

    hipLaunchKernelGGL(k_rules, dim3((DD_N * R_N / 4) / 256), dim3(256), 0, stream, rf, h);
    hipLaunchKernelGGL(k_kg,    dim3(NTOT / 64),              dim3(256), 0, stream,
                       inputs, embed, rel, dise, h);
    hipLaunchKernelGGL(k_mv,    dim3(NBLK_MV),                dim3(256), 0, stream, fcw, h, partials);
    hipLaunchKernelGGL(k_fin,   dim3(1),                      dim3(256), 0, stream,
                       partials, fcb, out);
}

// Round 3
// 169.993 us; speedup vs baseline: 1.5754x; 1.5754x over previous
//
#include <hip/hip_runtime.h>
#include <math.h>

namespace {
constexpr int S_N   = 4096;
constexpr int D_N   = 128;
constexpr int DD_N  = 64;
constexpr int REL_N = 8;
constexpr int R_N   = 512;
constexpr int NTOT  = S_N * REL_N;                        // 32768
constexpr int ROWLEN = R_N + NTOT;                        // 33280
constexpr long long FC_IN_N = (long long)DD_N * ROWLEN;   // 2,129,920
constexpr int CW    = 4096;                               // cols per k_mv block
constexpr int NCG   = (int)(FC_IN_N / CW);                // 520 (exact)
constexpr int RG    = 16;                                 // rows per k_mv block
constexpr int NBLK_MV = NCG * (DD_N / RG);                // 2080
typedef float floatx4 __attribute__((ext_vector_type(4)));
}

// h[dd*ROWLEN + c] = rule_features[dd*512 + c]   (c < 512)
__global__ __launch_bounds__(256) void k_rules(const float* __restrict__ rf,
                                               float* __restrict__ h) {
    int i  = blockIdx.x * 256 + threadIdx.x;   // float4 id, 8192 total
    int dd = i >> 7;                           // 128 float4 per rf row
    int c4 = i & 127;
    float4 v = reinterpret_cast<const float4*>(rf)[i];
    reinterpret_cast<float4*>(h)[(size_t)dd * (ROWLEN / 4) + c4] = v;
}

// kg[dd][n] = (dise[dd] . x[n]) / (||dise[dd]|| * ||x[n]||),  x[n] = mask[s]*(embed[s]+rel[r])
// written to h[dd*ROWLEN + 512 + n],  n = s*8 + r
__global__ __launch_bounds__(256) void k_kg(const int* __restrict__ inputs,
                                            const float* __restrict__ embed,
                                            const float* __restrict__ rel,
                                            const float* __restrict__ dise,
                                            float* __restrict__ h) {
    __shared__ __align__(16) float buf[64 * 129];  // dise staging (pad 129), then x tile [64][128]
    __shared__ float xsc[64];
    const int tid  = threadIdx.x;
    const int lane = tid & 63;
    const int wave = tid >> 6;
    const int n0   = blockIdx.x * 64;

    // 1) stage dise rows into LDS, pad-129 so per-row readout is 2-way (free)
    for (int i = tid; i < DD_N * D_N; i += 256) {
        buf[(i >> 7) * 129 + (i & 127)] = dise[i];
    }
    __syncthreads();

    // 2) my dise row (lane = dd) -> registers; dsc = 1/||dise[lane]||
    float dw[D_N];
    float dsq = 0.f;
    #pragma unroll
    for (int e = 0; e < D_N; ++e) {
        dw[e] = buf[lane * 129 + e];
        dsq += dw[e] * dw[e];
    }
    const float dsc = rsqrtf(dsq);
    __syncthreads();   // everyone done reading dise before buf is reused

    // 3) stage raw masked x tile into buf[0..8191]; per-row inverse norm in xsc
    {
        const int nl = tid >> 2, p = tid & 3;   // 4 threads per n-row, 32 elems each
        const int n = n0 + nl;
        const int s = n >> 3, r = n & 7;
        const float m = (inputs[s] != 0) ? 1.0f : 0.0f;
        const float4* es = reinterpret_cast<const float4*>(embed + (size_t)s * D_N);
        const float4* rs = reinterpret_cast<const float4*>(rel + (size_t)r * D_N);
        float4* xr = reinterpret_cast<float4*>(&buf[nl * D_N]);
        float sq = 0.f;
        #pragma unroll
        for (int i = 0; i < 8; ++i) {
            float4 a = es[p * 8 + i];
            float4 b = rs[p * 8 + i];
            float4 x;
            x.x = m * (a.x + b.x);
            x.y = m * (a.y + b.y);
            x.z = m * (a.z + b.z);
            x.w = m * (a.w + b.w);
            sq += x.x * x.x + x.y * x.y + x.z * x.z + x.w * x.w;
            xr[p * 8 + i] = x;
        }
        sq += __shfl_xor(sq, 1);   // 4-lane group shares one n-row
        sq += __shfl_xor(sq, 2);
        if (p == 0) xsc[nl] = (sq > 0.f) ? rsqrtf(sq) : 0.f;
    }
    __syncthreads();

    // 4) dots: lane = dd; this wave handles n-locals [wave*16, wave*16+16)
    //    x reads are all-lane-broadcast (conflict-free); dise comes from registers.
    //    Streaming stores per 4 j's to keep register pressure down (no acc[16]).
    float* dst = h + (size_t)lane * ROWLEN + R_N + n0 + wave * 16;
    #pragma unroll
    for (int j4 = 0; j4 < 4; ++j4) {
        float4 o;
        float* op = reinterpret_cast<float*>(&o);
        #pragma unroll
        for (int jj = 0; jj < 4; ++jj) {
            const int nl = wave * 16 + j4 * 4 + jj;
            const float4* xr = reinterpret_cast<const float4*>(&buf[nl * D_N]);
            float a0 = 0.f, a1 = 0.f, a2 = 0.f, a3 = 0.f;
            #pragma unroll
            for (int i = 0; i < 32; i += 4) {
                float4 x0 = xr[i], x1 = xr[i + 1], x2 = xr[i + 2], x3 = xr[i + 3];
                a0 += dw[4*i+ 0]*x0.x + dw[4*i+ 1]*x0.y + dw[4*i+ 2]*x0.z + dw[4*i+ 3]*x0.w;
                a1 += dw[4*i+ 4]*x1.x + dw[4*i+ 5]*x1.y + dw[4*i+ 6]*x1.z + dw[4*i+ 7]*x1.w;
                a2 += dw[4*i+ 8]*x2.x + dw[4*i+ 9]*x2.y + dw[4*i+10]*x2.z + dw[4*i+11]*x2.w;
                a3 += dw[4*i+12]*x3.x + dw[4*i+13]*x3.y + dw[4*i+14]*x3.z + dw[4*i+15]*x3.w;
            }
            op[jj] = (a0 + a1 + a2 + a3) * dsc * xsc[nl];
        }
        *reinterpret_cast<float4*>(dst + j4 * 4) = o;
    }
}

// block (cg, rg): out rows rg*16..rg*16+15, cols [cg*4096, (cg+1)*4096).
// Each row-chunk is 16 KB CONTIGUOUS; per-thread pure FMA accumulation,
// single reduction at block end. fc_w is streamed nontemporal (read-once,
// keep it out of L2/L3 so the h re-reads stay cached).
__global__ __launch_bounds__(256) void k_mv(const float* __restrict__ fcw,
                                            const float* __restrict__ h,
                                            float* __restrict__ partials) {
    const int tid = threadIdx.x;
    const int lane = tid & 63;
    const int wave = tid >> 6;
    const int cg = blockIdx.x >> 2;
    const int rg = blockIdx.x & 3;
    const size_t col0 = (size_t)cg * CW;

    const float4* hp = reinterpret_cast<const float4*>(h + col0);
    float4 h0 = hp[tid], h1 = hp[tid + 256], h2 = hp[tid + 512], h3 = hp[tid + 768];

    float acc[RG];
    #pragma unroll
    for (int k2 = 0; k2 < RG; ++k2) {
        const floatx4* wp = reinterpret_cast<const floatx4*>(
            fcw + (size_t)(rg * RG + k2) * FC_IN_N + col0);
        floatx4 w0 = __builtin_nontemporal_load(wp + tid);
        floatx4 w1 = __builtin_nontemporal_load(wp + tid + 256);
        floatx4 w2 = __builtin_nontemporal_load(wp + tid + 512);
        floatx4 w3 = __builtin_nontemporal_load(wp + tid + 768);
        float a;
        a  = w0.x*h0.x + w0.y*h0.y + w0.z*h0.z + w0.w*h0.w;
        a += w1.x*h1.x + w1.y*h1.y + w1.z*h1.z + w1.w*h1.w;
        a += w2.x*h2.x + w2.y*h2.y + w2.z*h2.z + w2.w*h2.w;
        a += w3.x*h3.x + w3.y*h3.y + w3.z*h3.z + w3.w*h3.w;
        acc[k2] = a;
    }

    __shared__ float red[4][RG];
    #pragma unroll
    for (int k2 = 0; k2 < RG; ++k2) {
        float a = acc[k2];
        #pragma unroll
        for (int m = 32; m >= 1; m >>= 1) a += __shfl_xor(a, m);
        if (lane == 0) red[wave][k2] = a;
    }
    __syncthreads();
    if (tid < RG) {
        float s = red[0][tid] + red[1][tid] + red[2][tid] + red[3][tid];
        // partials[cg*64 + (rg*16 + k2)] == partials[blockIdx.x*16 + k2]
        partials[(size_t)blockIdx.x * RG + tid] = s;
    }
}

// out[k] = sigmoid(fc_b[k] + sum_cg partials[cg*64 + k])
__global__ __launch_bounds__(256) void k_fin(const float* __restrict__ partials,
                                             const float* __restrict__ fcb,
                                             float* __restrict__ out) {
    const int tid = threadIdx.x;
    const int k = tid & 63, g = tid >> 6;
    float s = 0.f;
    for (int b = g; b < NCG; b += 4) s += partials[(size_t)b * 64 + k];
    __shared__ float red[4][64];
    red[g][k] = s;
    __syncthreads();
    if (tid < 64) {
        float t = red[0][tid] + red[1][tid] + red[2][tid] + red[3][tid] + fcb[tid];
        out[tid] = 1.0f / (1.0f + expf(-t));
    }
}

extern "C" void kernel_launch(void* const* d_in, const int* in_sizes, int n_in,
                              void* d_out, int out_size, void* d_ws, size_t ws_size,
                              hipStream_t stream) {
    const int*   inputs = (const int*)  d_in[0];
    const float* rf     = (const float*)d_in[1];
    const float* embed  = (const float*)d_in[2];
    const float* rel    = (const float*)d_in[3];
    const float* dise   = (const float*)d_in[4];
    const float* fcw    = (const float*)d_in[5];
    const float* fcb    = (const float*)d_in[6];
    float* out = (float*)d_out;

    // ws layout: h [FC_IN] floats, then partials [NBLK_MV*16] floats (~8.7 MB total)
    float* ws = (float*)d_ws;
    float* h        = ws;
    float* partials = ws + FC_IN_N;

    hipLaunchKernelGGL(k_rules, dim3((DD_N * R_N / 4) / 256), dim3(256), 0, stream, rf, h);
    hipLaunchKernelGGL(k_kg,    dim3(NTOT / 64),              dim3(256), 0, stream,
                       inputs, embed, rel, dise, h);
    hipLaunchKernelGGL(k_mv,    dim3(NBLK_MV),                dim3(256), 0, stream, fcw, h, partials);
    hipLaunchKernelGGL(k_fin,   dim3(1),                      dim3(256), 0, stream,
                       partials, fcb, out);
}

// Round 4
// 165.358 us; speedup vs baseline: 1.6196x; 1.0280x over previous
//
#include <hip/hip_runtime.h>
#include <math.h>

namespace {
constexpr int S_N   = 4096;
constexpr int D_N   = 128;
constexpr int DD_N  = 64;
constexpr int REL_N = 8;
constexpr int R_N   = 512;
constexpr int NTOT  = S_N * REL_N;                        // 32768
constexpr int ROWLEN = R_N + NTOT;                        // 33280
constexpr long long FC_IN_N = (long long)DD_N * ROWLEN;   // 2,129,920
constexpr int CW    = 4096;                               // cols per k_mv block
constexpr int NCG   = (int)(FC_IN_N / CW);                // 520 (exact)
constexpr int RG    = 16;                                 // rows per k_mv block
constexpr int NBLK_MV = NCG * (DD_N / RG);                // 2080 (mult of 8 -> bijective XCD swizzle)
typedef float floatx4 __attribute__((ext_vector_type(4)));

__device__ __forceinline__ float dot4(const float4& a, const float4& b) {
    return a.x*b.x + a.y*b.y + a.z*b.z + a.w*b.w;
}
}

// DE[dd][s] = dise[dd].embed[s]; block 0 also: dsc[dd]=1/||dise[dd]||, DR[dd][r]=dise[dd].rel[r]
__global__ __launch_bounds__(256) void k_pre1(const float* __restrict__ dise,
                                              const float* __restrict__ embed,
                                              const float* __restrict__ rel,
                                              float* __restrict__ DE,
                                              float* __restrict__ DR,
                                              float* __restrict__ dsc_g) {
    __shared__ float sd[DD_N * 129];                       // dise, pad 129 (2-way = free)
    __shared__ __align__(16) float se[64 * D_N];           // embed tile (broadcast reads)
    __shared__ __align__(16) float sr[REL_N * D_N];        // rel
    const int tid  = threadIdx.x;
    const int lane = tid & 63;
    const int wave = tid >> 6;
    const int s0   = blockIdx.x * 64;

    for (int i = tid; i < DD_N * D_N; i += 256)
        sd[(i >> 7) * 129 + (i & 127)] = dise[i];
    for (int i = tid; i < 64 * D_N / 4; i += 256)
        reinterpret_cast<float4*>(se)[i] =
            reinterpret_cast<const float4*>(embed + (size_t)s0 * D_N)[i];
    if (tid < REL_N * D_N / 4)
        reinterpret_cast<float4*>(sr)[tid] = reinterpret_cast<const float4*>(rel)[tid];
    __syncthreads();

    float dw[D_N];
    float dsq = 0.f;
    #pragma unroll
    for (int e = 0; e < D_N; ++e) {
        dw[e] = sd[lane * 129 + e];
        dsq += dw[e] * dw[e];
    }
    const float dsc = rsqrtf(dsq);

    if (blockIdx.x == 0) {
        if (wave == 0) dsc_g[lane] = dsc;
        // wave w computes DR for r = 2w, 2w+1 (broadcast LDS reads)
        #pragma unroll
        for (int rr = 0; rr < 2; ++rr) {
            const int r = wave * 2 + rr;
            float a = 0.f;
            #pragma unroll
            for (int e = 0; e < D_N; ++e) a += dw[e] * sr[r * D_N + e];
            DR[lane * REL_N + r] = a;
        }
    }

    // DE: wave handles s-locals [wave*16, wave*16+16); x reads broadcast, conflict-free
    float* dst = DE + (size_t)lane * S_N + s0 + wave * 16;
    #pragma unroll
    for (int j4 = 0; j4 < 4; ++j4) {
        float4 o;
        float* op = reinterpret_cast<float*>(&o);
        #pragma unroll
        for (int jj = 0; jj < 4; ++jj) {
            const int nl = wave * 16 + j4 * 4 + jj;
            const float4* xr = reinterpret_cast<const float4*>(&se[nl * D_N]);
            float a0 = 0.f, a1 = 0.f, a2 = 0.f, a3 = 0.f;
            #pragma unroll
            for (int i = 0; i < 32; i += 4) {
                float4 x0 = xr[i], x1 = xr[i + 1], x2 = xr[i + 2], x3 = xr[i + 3];
                a0 += dw[4*i+ 0]*x0.x + dw[4*i+ 1]*x0.y + dw[4*i+ 2]*x0.z + dw[4*i+ 3]*x0.w;
                a1 += dw[4*i+ 4]*x1.x + dw[4*i+ 5]*x1.y + dw[4*i+ 6]*x1.z + dw[4*i+ 7]*x1.w;
                a2 += dw[4*i+ 8]*x2.x + dw[4*i+ 9]*x2.y + dw[4*i+10]*x2.z + dw[4*i+11]*x2.w;
                a3 += dw[4*i+12]*x3.x + dw[4*i+13]*x3.y + dw[4*i+14]*x3.z + dw[4*i+15]*x3.w;
            }
            op[jj] = a0 + a1 + a2 + a3;
        }
        *reinterpret_cast<float4*>(dst + j4 * 4) = o;
    }
}

// xinv[n] = mask[s] && sq>0 ? rsqrt(||e_s||^2 + 2 e_s.rel_r + ||rel_r||^2) : 0
__global__ __launch_bounds__(256) void k_pre0(const int* __restrict__ inputs,
                                              const float* __restrict__ embed,
                                              const float* __restrict__ rel,
                                              float* __restrict__ xinv) {
    __shared__ __align__(16) float sr[REL_N * D_N];
    __shared__ float rr[REL_N];
    const int tid = threadIdx.x;
    const int p  = tid & 3;       // quarter of the 128-dim
    const int sl = tid >> 2;      // 0..63
    const int s  = blockIdx.x * 64 + sl;

    if (tid < REL_N * D_N / 4)
        reinterpret_cast<float4*>(sr)[tid] = reinterpret_cast<const float4*>(rel)[tid];
    __syncthreads();
    if (tid < REL_N) {
        float a = 0.f;
        for (int e = 0; e < D_N; ++e) { float v = sr[tid * D_N + e]; a += v * v; }
        rr[tid] = a;
    }
    __syncthreads();

    float4 e4[8];
    const float4* ep = reinterpret_cast<const float4*>(embed + (size_t)s * D_N + p * 32);
    #pragma unroll
    for (int i = 0; i < 8; ++i) e4[i] = ep[i];
    float ee = 0.f;
    #pragma unroll
    for (int i = 0; i < 8; ++i) ee += dot4(e4[i], e4[i]);

    const float4* sr4 = reinterpret_cast<const float4*>(sr);
    float er[8];
    #pragma unroll
    for (int r = 0; r < REL_N; ++r) {
        float a = 0.f;
        #pragma unroll
        for (int i = 0; i < 8; ++i) a += dot4(e4[i], sr4[r * 32 + p * 8 + i]);
        er[r] = a;
    }

    ee += __shfl_xor(ee, 1); ee += __shfl_xor(ee, 2);
    #pragma unroll
    for (int r = 0; r < REL_N; ++r) {
        er[r] += __shfl_xor(er[r], 1);
        er[r] += __shfl_xor(er[r], 2);
    }

    if (p == 0) {
        const bool m = (inputs[s] != 0);
        float vr[8];
        #pragma unroll
        for (int r = 0; r < REL_N; ++r) {
            float sq = ee + 2.f * er[r] + rr[r];
            vr[r] = (m && sq > 0.f) ? rsqrtf(sq) : 0.f;
        }
        float4 o0, o1;
        o0.x = vr[0]; o0.y = vr[1]; o0.z = vr[2]; o0.w = vr[3];
        o1.x = vr[4]; o1.y = vr[5]; o1.z = vr[6]; o1.w = vr[7];
        float4* xp = reinterpret_cast<float4*>(xinv + (size_t)s * REL_N);
        xp[0] = o0; xp[1] = o1;
    }
}

// h kg block: h[dd*ROWLEN+512+n] = dsc[dd]*xinv[n]*(DE[dd][s]+DR[dd][r]); q==0 also copies rules row
__global__ __launch_bounds__(256) void k_kg2(const float* __restrict__ rf,
                                             const float* __restrict__ DE,
                                             const float* __restrict__ DR,
                                             const float* __restrict__ dsc_g,
                                             const float* __restrict__ xinv,
                                             float* __restrict__ h) {
    __shared__ __align__(16) float sx[8192];
    __shared__ float sD[1024];
    const int tid = threadIdx.x;
    const int dd  = blockIdx.x >> 2;
    const int q   = blockIdx.x & 3;
    const int n0  = q * 8192;
    const int s0  = q * 1024;

    for (int i = tid; i < 2048; i += 256)
        reinterpret_cast<float4*>(sx)[i] = reinterpret_cast<const float4*>(xinv + n0)[i];
    if (tid < 256)
        reinterpret_cast<float4*>(sD)[tid] =
            reinterpret_cast<const float4*>(DE + (size_t)dd * S_N + s0)[tid];
    const float dsc = dsc_g[dd];
    const float4 drlo = reinterpret_cast<const float4*>(DR + dd * REL_N)[0];
    const float4 drhi = reinterpret_cast<const float4*>(DR + dd * REL_N)[1];
    const float4 drv = (tid & 1) ? drhi : drlo;   // r-base is 4*(tid&1), thread-constant
    __syncthreads();

    float* hb = h + (size_t)dd * ROWLEN + R_N + n0;
    #pragma unroll
    for (int i = 0; i < 8; ++i) {
        const int f4i = i * 256 + tid;            // float4 index, lanes consecutive
        const int ln  = f4i * 4;
        const float de = sD[f4i >> 1];            // s-local = ln>>3
        float4 xv = reinterpret_cast<const float4*>(sx)[f4i];
        float4 o;
        o.x = dsc * xv.x * (de + drv.x);
        o.y = dsc * xv.y * (de + drv.y);
        o.z = dsc * xv.z * (de + drv.z);
        o.w = dsc * xv.w * (de + drv.w);
        *reinterpret_cast<float4*>(hb + ln) = o;
    }
    if (q == 0 && tid < 128)
        reinterpret_cast<float4*>(h + (size_t)dd * ROWLEN)[tid] =
            reinterpret_cast<const float4*>(rf + (size_t)dd * R_N)[tid];
}

// block (cg, rg) after XCD swizzle: rows rg*16..+15, cols [cg*4096, (cg+1)*4096)
__global__ __launch_bounds__(256) void k_mv(const float* __restrict__ fcw,
                                            const float* __restrict__ h,
                                            float* __restrict__ partials) {
    const int tid = threadIdx.x;
    const int lane = tid & 63;
    const int wave = tid >> 6;
    // bijective XCD swizzle: blocks sharing an h chunk (same cg) land on one XCD's L2
    const int swz = (blockIdx.x & 7) * (NBLK_MV / 8) + (blockIdx.x >> 3);
    const int cg = swz >> 2;
    const int rg = swz & 3;
    const size_t col0 = (size_t)cg * CW;

    const float4* hp = reinterpret_cast<const float4*>(h + col0);
    float4 h0 = hp[tid], h1 = hp[tid + 256], h2 = hp[tid + 512], h3 = hp[tid + 768];

    float acc[RG];
    #pragma unroll
    for (int k2 = 0; k2 < RG; ++k2) {
        const floatx4* wp = reinterpret_cast<const floatx4*>(
            fcw + (size_t)(rg * RG + k2) * FC_IN_N + col0);
        floatx4 w0 = __builtin_nontemporal_load(wp + tid);
        floatx4 w1 = __builtin_nontemporal_load(wp + tid + 256);
        floatx4 w2 = __builtin_nontemporal_load(wp + tid + 512);
        floatx4 w3 = __builtin_nontemporal_load(wp + tid + 768);
        float a;
        a  = w0.x*h0.x + w0.y*h0.y + w0.z*h0.z + w0.w*h0.w;
        a += w1.x*h1.x + w1.y*h1.y + w1.z*h1.z + w1.w*h1.w;
        a += w2.x*h2.x + w2.y*h2.y + w2.z*h2.z + w2.w*h2.w;
        a += w3.x*h3.x + w3.y*h3.y + w3.z*h3.z + w3.w*h3.w;
        acc[k2] = a;
    }

    __shared__ float red[4][RG];
    #pragma unroll
    for (int k2 = 0; k2 < RG; ++k2) {
        float a = acc[k2];
        #pragma unroll
        for (int m = 32; m >= 1; m >>= 1) a += __shfl_xor(a, m);
        if (lane == 0) red[wave][k2] = a;
    }
    __syncthreads();
    if (tid < RG) {
        float s = red[0][tid] + red[1][tid] + red[2][tid] + red[3][tid];
        partials[(size_t)swz * RG + tid] = s;   // == partials[cg*64 + rg*16 + tid]
    }
}

// out[k] = sigmoid(fc_b[k] + sum_cg partials[cg*64 + k])
__global__ __launch_bounds__(256) void k_fin(const float* __restrict__ partials,
                                             const float* __restrict__ fcb,
                                             float* __restrict__ out) {
    const int tid = threadIdx.x;
    const int k = tid & 63, g = tid >> 6;
    float s = 0.f;
    for (int b = g; b < NCG; b += 4) s += partials[(size_t)b * 64 + k];
    __shared__ float red[4][64];
    red[g][k] = s;
    __syncthreads();
    if (tid < 64) {
        float t = red[0][tid] + red[1][tid] + red[2][tid] + red[3][tid] + fcb[tid];
        out[tid] = 1.0f / (1.0f + expf(-t));
    }
}

extern "C" void kernel_launch(void* const* d_in, const int* in_sizes, int n_in,
                              void* d_out, int out_size, void* d_ws, size_t ws_size,
                              hipStream_t stream) {
    const int*   inputs = (const int*)  d_in[0];
    const float* rf     = (const float*)d_in[1];
    const float* embed  = (const float*)d_in[2];
    const float* rel    = (const float*)d_in[3];
    const float* dise   = (const float*)d_in[4];
    const float* fcw    = (const float*)d_in[5];
    const float* fcb    = (const float*)d_in[6];
    float* out = (float*)d_out;

    // ws layout (floats): h[FC_IN] | partials[NCG*64] | DE[64*4096] | DR[64*8] | dsc[64] | xinv[32768]
    float* ws = (float*)d_ws;
    float* h        = ws;
    float* partials = h + FC_IN_N;
    float* DE       = partials + (size_t)NCG * 64;
    float* DR       = DE + (size_t)DD_N * S_N;
    float* dsc_g    = DR + DD_N * REL_N;
    float* xinv     = dsc_g + 64;

    hipLaunchKernelGGL(k_pre1, dim3(S_N / 64), dim3(256), 0, stream, dise, embed, rel, DE, DR, dsc_g);
    hipLaunchKernelGGL(k_pre0, dim3(S_N / 64), dim3(256), 0, stream, inputs, embed, rel, xinv);
    hipLaunchKernelGGL(k_kg2,  dim3(DD_N * 4), dim3(256), 0, stream, rf, DE, DR, dsc_g, xinv, h);
    hipLaunchKernelGGL(k_mv,   dim3(NBLK_MV),  dim3(256), 0, stream, fcw, h, partials);
    hipLaunchKernelGGL(k_fin,  dim3(1),        dim3(256), 0, stream, partials, fcb, out);
}

// Round 5
// 126.554 us; speedup vs baseline: 2.1162x; 1.3066x over previous
//
#include <hip/hip_runtime.h>
#include <math.h>

namespace {
constexpr int S_N   = 4096;
constexpr int D_N   = 128;
constexpr int DD_N  = 64;
constexpr int REL_N = 8;
constexpr int R_N   = 512;
constexpr int NTOT  = S_N * REL_N;                        // 32768
constexpr int ROWLEN = R_N + NTOT;                        // 33280
constexpr long long FC_IN_N = (long long)DD_N * ROWLEN;   // 2,129,920
constexpr int NCH   = 32;                                 // col chunks per w-row
constexpr int CHUNK2 = (int)(FC_IN_N / NCH);              // 66,560 floats = 260 KB = exactly 2 h-rows
constexpr int NBLK2 = NCH * DD_N;                         // 2048 blocks (full residency, mult of 8)
typedef float floatx4 __attribute__((ext_vector_type(4)));

__device__ __forceinline__ float dot4(const float4& a, const float4& b) {
    return a.x*b.x + a.y*b.y + a.z*b.z + a.w*b.w;
}
}

// DE[dd][s] = dise[dd].embed[s]; block 0 also: dsc[dd]=1/||dise[dd]||, DR[dd][r]=dise[dd].rel[r]
__global__ __launch_bounds__(256) void k_pre1(const float* __restrict__ dise,
                                              const float* __restrict__ embed,
                                              const float* __restrict__ rel,
                                              float* __restrict__ DE,
                                              float* __restrict__ DR,
                                              float* __restrict__ dsc_g) {
    __shared__ float sd[DD_N * 129];                       // dise, pad 129 (2-way = free)
    __shared__ __align__(16) float se[64 * D_N];           // embed tile (broadcast reads)
    __shared__ __align__(16) float sr[REL_N * D_N];        // rel
    const int tid  = threadIdx.x;
    const int lane = tid & 63;
    const int wave = tid >> 6;
    const int s0   = blockIdx.x * 64;

    for (int i = tid; i < DD_N * D_N; i += 256)
        sd[(i >> 7) * 129 + (i & 127)] = dise[i];
    for (int i = tid; i < 64 * D_N / 4; i += 256)
        reinterpret_cast<float4*>(se)[i] =
            reinterpret_cast<const float4*>(embed + (size_t)s0 * D_N)[i];
    if (tid < REL_N * D_N / 4)
        reinterpret_cast<float4*>(sr)[tid] = reinterpret_cast<const float4*>(rel)[tid];
    __syncthreads();

    float dw[D_N];
    float dsq = 0.f;
    #pragma unroll
    for (int e = 0; e < D_N; ++e) {
        dw[e] = sd[lane * 129 + e];
        dsq += dw[e] * dw[e];
    }
    const float dsc = rsqrtf(dsq);

    if (blockIdx.x == 0) {
        if (wave == 0) dsc_g[lane] = dsc;
        // wave w computes DR for r = 2w, 2w+1 (broadcast LDS reads)
        #pragma unroll
        for (int rr = 0; rr < 2; ++rr) {
            const int r = wave * 2 + rr;
            float a = 0.f;
            #pragma unroll
            for (int e = 0; e < D_N; ++e) a += dw[e] * sr[r * D_N + e];
            DR[lane * REL_N + r] = a;
        }
    }

    // DE: wave handles s-locals [wave*16, wave*16+16); x reads broadcast, conflict-free
    float* dst = DE + (size_t)lane * S_N + s0 + wave * 16;
    #pragma unroll
    for (int j4 = 0; j4 < 4; ++j4) {
        float4 o;
        float* op = reinterpret_cast<float*>(&o);
        #pragma unroll
        for (int jj = 0; jj < 4; ++jj) {
            const int nl = wave * 16 + j4 * 4 + jj;
            const float4* xr = reinterpret_cast<const float4*>(&se[nl * D_N]);
            float a0 = 0.f, a1 = 0.f, a2 = 0.f, a3 = 0.f;
            #pragma unroll
            for (int i = 0; i < 32; i += 4) {
                float4 x0 = xr[i], x1 = xr[i + 1], x2 = xr[i + 2], x3 = xr[i + 3];
                a0 += dw[4*i+ 0]*x0.x + dw[4*i+ 1]*x0.y + dw[4*i+ 2]*x0.z + dw[4*i+ 3]*x0.w;
                a1 += dw[4*i+ 4]*x1.x + dw[4*i+ 5]*x1.y + dw[4*i+ 6]*x1.z + dw[4*i+ 7]*x1.w;
                a2 += dw[4*i+ 8]*x2.x + dw[4*i+ 9]*x2.y + dw[4*i+10]*x2.z + dw[4*i+11]*x2.w;
                a3 += dw[4*i+12]*x3.x + dw[4*i+13]*x3.y + dw[4*i+14]*x3.z + dw[4*i+15]*x3.w;
            }
            op[jj] = a0 + a1 + a2 + a3;
        }
        *reinterpret_cast<float4*>(dst + j4 * 4) = o;
    }
}

// xinv[n] = mask[s] && sq>0 ? rsqrt(||e_s||^2 + 2 e_s.rel_r + ||rel_r||^2) : 0
__global__ __launch_bounds__(256) void k_pre0(const int* __restrict__ inputs,
                                              const float* __restrict__ embed,
                                              const float* __restrict__ rel,
                                              float* __restrict__ xinv) {
    __shared__ __align__(16) float sr[REL_N * D_N];
    __shared__ float rr[REL_N];
    const int tid = threadIdx.x;
    const int p  = tid & 3;       // quarter of the 128-dim
    const int sl = tid >> 2;      // 0..63
    const int s  = blockIdx.x * 64 + sl;

    if (tid < REL_N * D_N / 4)
        reinterpret_cast<float4*>(sr)[tid] = reinterpret_cast<const float4*>(rel)[tid];
    __syncthreads();
    if (tid < REL_N) {
        float a = 0.f;
        for (int e = 0; e < D_N; ++e) { float v = sr[tid * D_N + e]; a += v * v; }
        rr[tid] = a;
    }
    __syncthreads();

    float4 e4[8];
    const float4* ep = reinterpret_cast<const float4*>(embed + (size_t)s * D_N + p * 32);
    #pragma unroll
    for (int i = 0; i < 8; ++i) e4[i] = ep[i];
    float ee = 0.f;
    #pragma unroll
    for (int i = 0; i < 8; ++i) ee += dot4(e4[i], e4[i]);

    const float4* sr4 = reinterpret_cast<const float4*>(sr);
    float er[8];
    #pragma unroll
    for (int r = 0; r < REL_N; ++r) {
        float a = 0.f;
        #pragma unroll
        for (int i = 0; i < 8; ++i) a += dot4(e4[i], sr4[r * 32 + p * 8 + i]);
        er[r] = a;
    }

    ee += __shfl_xor(ee, 1); ee += __shfl_xor(ee, 2);
    #pragma unroll
    for (int r = 0; r < REL_N; ++r) {
        er[r] += __shfl_xor(er[r], 1);
        er[r] += __shfl_xor(er[r], 2);
    }

    if (p == 0) {
        const bool m = (inputs[s] != 0);
        float vr[8];
        #pragma unroll
        for (int r = 0; r < REL_N; ++r) {
            float sq = ee + 2.f * er[r] + rr[r];
            vr[r] = (m && sq > 0.f) ? rsqrtf(sq) : 0.f;
        }
        float4 o0, o1;
        o0.x = vr[0]; o0.y = vr[1]; o0.z = vr[2]; o0.w = vr[3];
        o1.x = vr[4]; o1.y = vr[5]; o1.z = vr[6]; o1.w = vr[7];
        float4* xp = reinterpret_cast<float4*>(xinv + (size_t)s * REL_N);
        xp[0] = o0; xp[1] = o1;
    }
}

// h kg block: h[dd*ROWLEN+512+n] = dsc[dd]*xinv[n]*(DE[dd][s]+DR[dd][r]); q==0 also copies rules row
__global__ __launch_bounds__(256) void k_kg2(const float* __restrict__ rf,
                                             const float* __restrict__ DE,
                                             const float* __restrict__ DR,
                                             const float* __restrict__ dsc_g,
                                             const float* __restrict__ xinv,
                                             float* __restrict__ h) {
    __shared__ __align__(16) float sx[8192];
    __shared__ float sD[1024];
    const int tid = threadIdx.x;
    const int dd  = blockIdx.x >> 2;
    const int q   = blockIdx.x & 3;
    const int n0  = q * 8192;
    const int s0  = q * 1024;

    for (int i = tid; i < 2048; i += 256)
        reinterpret_cast<float4*>(sx)[i] = reinterpret_cast<const float4*>(xinv + n0)[i];
    if (tid < 256)
        reinterpret_cast<float4*>(sD)[tid] =
            reinterpret_cast<const float4*>(DE + (size_t)dd * S_N + s0)[tid];
    const float dsc = dsc_g[dd];
    const float4 drlo = reinterpret_cast<const float4*>(DR + dd * REL_N)[0];
    const float4 drhi = reinterpret_cast<const float4*>(DR + dd * REL_N)[1];
    const float4 drv = (tid & 1) ? drhi : drlo;   // r-base is 4*(tid&1), thread-constant
    __syncthreads();

    float* hb = h + (size_t)dd * ROWLEN + R_N + n0;
    #pragma unroll
    for (int i = 0; i < 8; ++i) {
        const int f4i = i * 256 + tid;            // float4 index, lanes consecutive
        const int ln  = f4i * 4;
        const float de = sD[f4i >> 1];            // s-local = ln>>3
        float4 xv = reinterpret_cast<const float4*>(sx)[f4i];
        float4 o;
        o.x = dsc * xv.x * (de + drv.x);
        o.y = dsc * xv.y * (de + drv.y);
        o.z = dsc * xv.z * (de + drv.z);
        o.w = dsc * xv.w * (de + drv.w);
        *reinterpret_cast<float4*>(hb + ln) = o;
    }
    if (q == 0 && tid < 128)
        reinterpret_cast<float4*>(h + (size_t)dd * ROWLEN)[tid] =
            reinterpret_cast<const float4*>(rf + (size_t)dd * R_N)[tid];
}

// block (k, c) after XCD swizzle: out row k, cols [c*66560, (c+1)*66560).
// ONE contiguous 260 KB nontemporal w-stream per block; h chunk (= h rows 2c,2c+1)
// is shared by the 64 same-c blocks, clustered on one XCD -> L2-served.
__global__ __launch_bounds__(256, 8) void k_mv(const float* __restrict__ fcw,
                                               const float* __restrict__ h,
                                               float* __restrict__ partials) {
    const int tid = threadIdx.x;
    // bijective XCD swizzle (2048 % 8 == 0): chunk c's 64 blocks share one XCD
    const int swz = (blockIdx.x & 7) * (NBLK2 / 8) + (blockIdx.x >> 3);
    const int c = swz >> 6;
    const int k = swz & 63;

    const float4*  hp = reinterpret_cast<const float4*>(h) + (size_t)c * (CHUNK2 / 4);
    const floatx4* wp = reinterpret_cast<const floatx4*>(fcw + (size_t)k * FC_IN_N)
                        + (size_t)c * (CHUNK2 / 4);

    float a = 0.f;
    #pragma unroll 5
    for (int i = 0; i < CHUNK2 / 4 / 256; ++i) {   // 65 iterations
        const int idx = i * 256 + tid;
        floatx4 w = __builtin_nontemporal_load(wp + idx);
        float4 hv = hp[idx];
        a += w.x * hv.x + w.y * hv.y + w.z * hv.z + w.w * hv.w;
    }

    #pragma unroll
    for (int m = 32; m >= 1; m >>= 1) a += __shfl_xor(a, m);
    __shared__ float red[4];
    if ((tid & 63) == 0) red[tid >> 6] = a;
    __syncthreads();
    if (tid == 0) partials[swz] = red[0] + red[1] + red[2] + red[3];
}

// out[k] = sigmoid(fc_b[k] + sum_c partials[c*64 + k])
__global__ __launch_bounds__(256) void k_fin(const float* __restrict__ partials,
                                             const float* __restrict__ fcb,
                                             float* __restrict__ out) {
    const int tid = threadIdx.x;
    const int k = tid & 63, g = tid >> 6;
    float s = 0.f;
    for (int b = g; b < NCH; b += 4) s += partials[(size_t)b * 64 + k];
    __shared__ float red[4][64];
    red[g][k] = s;
    __syncthreads();
    if (tid < 64) {
        float t = red[0][tid] + red[1][tid] + red[2][tid] + red[3][tid] + fcb[tid];
        out[tid] = 1.0f / (1.0f + expf(-t));
    }
}

extern "C" void kernel_launch(void* const* d_in, const int* in_sizes, int n_in,
                              void* d_out, int out_size, void* d_ws, size_t ws_size,
                              hipStream_t stream) {
    const int*   inputs = (const int*)  d_in[0];
    const float* rf     = (const float*)d_in[1];
    const float* embed  = (const float*)d_in[2];
    const float* rel    = (const float*)d_in[3];
    const float* dise   = (const float*)d_in[4];
    const float* fcw    = (const float*)d_in[5];
    const float* fcb    = (const float*)d_in[6];
    float* out = (float*)d_out;

    // ws layout (floats): h[FC_IN] | partials[NBLK2] | DE[64*4096] | DR[64*8] | dsc[64] | xinv[32768]
    float* ws = (float*)d_ws;
    float* h        = ws;
    float* partials = h + FC_IN_N;
    float* DE       = partials + NBLK2;
    float* DR       = DE + (size_t)DD_N * S_N;
    float* dsc_g    = DR + DD_N * REL_N;
    float* xinv     = dsc_g + 64;

    hipLaunchKernelGGL(k_pre1, dim3(S_N / 64), dim3(256), 0, stream, dise, embed, rel, DE, DR, dsc_g);
    hipLaunchKernelGGL(k_pre0, dim3(S_N / 64), dim3(256), 0, stream, inputs, embed, rel, xinv);
    hipLaunchKernelGGL(k_kg2,  dim3(DD_N * 4), dim3(256), 0, stream, rf, DE, DR, dsc_g, xinv, h);
    hipLaunchKernelGGL(k_mv,   dim3(NBLK2),    dim3(256), 0, stream, fcw, h, partials);
    hipLaunchKernelGGL(k_fin,  dim3(1),        dim3(256), 0, stream, partials, fcb, out);
}

// Round 6
// 117.928 us; speedup vs baseline: 2.2710x; 1.0732x over previous
//
#include <hip/hip_runtime.h>
#include <math.h>

namespace {
constexpr int S_N   = 4096;
constexpr int D_N   = 128;
constexpr int DD_N  = 64;
constexpr int REL_N = 8;
constexpr int R_N   = 512;
constexpr int NTOT  = S_N * REL_N;                        // 32768
constexpr int ROWLEN = R_N + NTOT;                        // 33280
constexpr long long FC_IN_N = (long long)DD_N * ROWLEN;   // 2,129,920
constexpr int NCH   = 32;                                 // col chunks per w-row
constexpr int CHUNK2 = (int)(FC_IN_N / NCH);              // 66,560 floats = 260 KB = exactly 2 h-rows
constexpr int RPB   = 4;                                  // output rows per k_mv block
constexpr int KG_N  = DD_N / RPB;                         // 16 k-groups
constexpr int NBLK3 = NCH * KG_N;                         // 512 blocks (mult of 8)
typedef float floatx4 __attribute__((ext_vector_type(4)));

__device__ __forceinline__ float dot4(const float4& a, const float4& b) {
    return a.x*b.x + a.y*b.y + a.z*b.z + a.w*b.w;
}
}

// DE[dd][s] = dise[dd].embed[s]; block 0 also: dsc[dd]=1/||dise[dd]||, DR[dd][r]=dise[dd].rel[r]
__global__ __launch_bounds__(256) void k_pre1(const float* __restrict__ dise,
                                              const float* __restrict__ embed,
                                              const float* __restrict__ rel,
                                              float* __restrict__ DE,
                                              float* __restrict__ DR,
                                              float* __restrict__ dsc_g) {
    __shared__ float sd[DD_N * 129];                       // dise, pad 129 (2-way = free)
    __shared__ __align__(16) float se[64 * D_N];           // embed tile (broadcast reads)
    __shared__ __align__(16) float sr[REL_N * D_N];        // rel
    const int tid  = threadIdx.x;
    const int lane = tid & 63;
    const int wave = tid >> 6;
    const int s0   = blockIdx.x * 64;

    for (int i = tid; i < DD_N * D_N; i += 256)
        sd[(i >> 7) * 129 + (i & 127)] = dise[i];
    for (int i = tid; i < 64 * D_N / 4; i += 256)
        reinterpret_cast<float4*>(se)[i] =
            reinterpret_cast<const float4*>(embed + (size_t)s0 * D_N)[i];
    if (tid < REL_N * D_N / 4)
        reinterpret_cast<float4*>(sr)[tid] = reinterpret_cast<const float4*>(rel)[tid];
    __syncthreads();

    float dw[D_N];
    float dsq = 0.f;
    #pragma unroll
    for (int e = 0; e < D_N; ++e) {
        dw[e] = sd[lane * 129 + e];
        dsq += dw[e] * dw[e];
    }
    const float dsc = rsqrtf(dsq);

    if (blockIdx.x == 0) {
        if (wave == 0) dsc_g[lane] = dsc;
        // wave w computes DR for r = 2w, 2w+1 (broadcast LDS reads)
        #pragma unroll
        for (int rr = 0; rr < 2; ++rr) {
            const int r = wave * 2 + rr;
            float a = 0.f;
            #pragma unroll
            for (int e = 0; e < D_N; ++e) a += dw[e] * sr[r * D_N + e];
            DR[lane * REL_N + r] = a;
        }
    }

    // DE: wave handles s-locals [wave*16, wave*16+16); x reads broadcast, conflict-free
    float* dst = DE + (size_t)lane * S_N + s0 + wave * 16;
    #pragma unroll
    for (int j4 = 0; j4 < 4; ++j4) {
        float4 o;
        float* op = reinterpret_cast<float*>(&o);
        #pragma unroll
        for (int jj = 0; jj < 4; ++jj) {
            const int nl = wave * 16 + j4 * 4 + jj;
            const float4* xr = reinterpret_cast<const float4*>(&se[nl * D_N]);
            float a0 = 0.f, a1 = 0.f, a2 = 0.f, a3 = 0.f;
            #pragma unroll
            for (int i = 0; i < 32; i += 4) {
                float4 x0 = xr[i], x1 = xr[i + 1], x2 = xr[i + 2], x3 = xr[i + 3];
                a0 += dw[4*i+ 0]*x0.x + dw[4*i+ 1]*x0.y + dw[4*i+ 2]*x0.z + dw[4*i+ 3]*x0.w;
                a1 += dw[4*i+ 4]*x1.x + dw[4*i+ 5]*x1.y + dw[4*i+ 6]*x1.z + dw[4*i+ 7]*x1.w;
                a2 += dw[4*i+ 8]*x2.x + dw[4*i+ 9]*x2.y + dw[4*i+10]*x2.z + dw[4*i+11]*x2.w;
                a3 += dw[4*i+12]*x3.x + dw[4*i+13]*x3.y + dw[4*i+14]*x3.z + dw[4*i+15]*x3.w;
            }
            op[jj] = a0 + a1 + a2 + a3;
        }
        *reinterpret_cast<float4*>(dst + j4 * 4) = o;
    }
}

// xinv[n] = mask[s] && sq>0 ? rsqrt(||e_s||^2 + 2 e_s.rel_r + ||rel_r||^2) : 0
__global__ __launch_bounds__(256) void k_pre0(const int* __restrict__ inputs,
                                              const float* __restrict__ embed,
                                              const float* __restrict__ rel,
                                              float* __restrict__ xinv) {
    __shared__ __align__(16) float sr[REL_N * D_N];
    __shared__ float rr[REL_N];
    const int tid = threadIdx.x;
    const int p  = tid & 3;       // quarter of the 128-dim
    const int sl = tid >> 2;      // 0..63
    const int s  = blockIdx.x * 64 + sl;

    if (tid < REL_N * D_N / 4)
        reinterpret_cast<float4*>(sr)[tid] = reinterpret_cast<const float4*>(rel)[tid];
    __syncthreads();
    if (tid < REL_N) {
        float a = 0.f;
        for (int e = 0; e < D_N; ++e) { float v = sr[tid * D_N + e]; a += v * v; }
        rr[tid] = a;
    }
    __syncthreads();

    float4 e4[8];
    const float4* ep = reinterpret_cast<const float4*>(embed + (size_t)s * D_N + p * 32);
    #pragma unroll
    for (int i = 0; i < 8; ++i) e4[i] = ep[i];
    float ee = 0.f;
    #pragma unroll
    for (int i = 0; i < 8; ++i) ee += dot4(e4[i], e4[i]);

    const float4* sr4 = reinterpret_cast<const float4*>(sr);
    float er[8];
    #pragma unroll
    for (int r = 0; r < REL_N; ++r) {
        float a = 0.f;
        #pragma unroll
        for (int i = 0; i < 8; ++i) a += dot4(e4[i], sr4[r * 32 + p * 8 + i]);
        er[r] = a;
    }

    ee += __shfl_xor(ee, 1); ee += __shfl_xor(ee, 2);
    #pragma unroll
    for (int r = 0; r < REL_N; ++r) {
        er[r] += __shfl_xor(er[r], 1);
        er[r] += __shfl_xor(er[r], 2);
    }

    if (p == 0) {
        const bool m = (inputs[s] != 0);
        float vr[8];
        #pragma unroll
        for (int r = 0; r < REL_N; ++r) {
            float sq = ee + 2.f * er[r] + rr[r];
            vr[r] = (m && sq > 0.f) ? rsqrtf(sq) : 0.f;
        }
        float4 o0, o1;
        o0.x = vr[0]; o0.y = vr[1]; o0.z = vr[2]; o0.w = vr[3];
        o1.x = vr[4]; o1.y = vr[5]; o1.z = vr[6]; o1.w = vr[7];
        float4* xp = reinterpret_cast<float4*>(xinv + (size_t)s * REL_N);
        xp[0] = o0; xp[1] = o1;
    }
}

// h kg block: h[dd*ROWLEN+512+n] = dsc[dd]*xinv[n]*(DE[dd][s]+DR[dd][r]); q==0 also copies rules row
__global__ __launch_bounds__(256) void k_kg2(const float* __restrict__ rf,
                                             const float* __restrict__ DE,
                                             const float* __restrict__ DR,
                                             const float* __restrict__ dsc_g,
                                             const float* __restrict__ xinv,
                                             float* __restrict__ h) {
    __shared__ __align__(16) float sx[8192];
    __shared__ float sD[1024];
    const int tid = threadIdx.x;
    const int dd  = blockIdx.x >> 2;
    const int q   = blockIdx.x & 3;
    const int n0  = q * 8192;
    const int s0  = q * 1024;

    for (int i = tid; i < 2048; i += 256)
        reinterpret_cast<float4*>(sx)[i] = reinterpret_cast<const float4*>(xinv + n0)[i];
    if (tid < 256)
        reinterpret_cast<float4*>(sD)[tid] =
            reinterpret_cast<const float4*>(DE + (size_t)dd * S_N + s0)[tid];
    const float dsc = dsc_g[dd];
    const float4 drlo = reinterpret_cast<const float4*>(DR + dd * REL_N)[0];
    const float4 drhi = reinterpret_cast<const float4*>(DR + dd * REL_N)[1];
    const float4 drv = (tid & 1) ? drhi : drlo;   // r-base is 4*(tid&1), thread-constant
    __syncthreads();

    float* hb = h + (size_t)dd * ROWLEN + R_N + n0;
    #pragma unroll
    for (int i = 0; i < 8; ++i) {
        const int f4i = i * 256 + tid;            // float4 index, lanes consecutive
        const int ln  = f4i * 4;
        const float de = sD[f4i >> 1];            // s-local = ln>>3
        float4 xv = reinterpret_cast<const float4*>(sx)[f4i];
        float4 o;
        o.x = dsc * xv.x * (de + drv.x);
        o.y = dsc * xv.y * (de + drv.y);
        o.z = dsc * xv.z * (de + drv.z);
        o.w = dsc * xv.w * (de + drv.w);
        *reinterpret_cast<float4*>(hb + ln) = o;
    }
    if (q == 0 && tid < 128)
        reinterpret_cast<float4*>(h + (size_t)dd * ROWLEN)[tid] =
            reinterpret_cast<const float4*>(rf + (size_t)dd * R_N)[tid];
}

// block (kg, c) after XCD swizzle: out rows kg*4..kg*4+3, cols [c*66560, (c+1)*66560).
// 4 contiguous 260 KB nontemporal w-streams per block; each h float4 loaded once
// feeds 4 rows -> h L2 traffic /4 vs RPB=1. Same total stream count (2048).
__global__ __launch_bounds__(256, 2) void k_mv(const float* __restrict__ fcw,
                                               const float* __restrict__ h,
                                               float* __restrict__ partials) {
    const int tid = threadIdx.x;
    // bijective XCD swizzle (512 % 8 == 0): chunk c's 16 blocks cluster per XCD
    const int swz = (blockIdx.x & 7) * (NBLK3 / 8) + (blockIdx.x >> 3);
    const int c  = swz >> 4;      // 0..31
    const int kg = swz & 15;      // 0..15

    const float4* hp = reinterpret_cast<const float4*>(h) + (size_t)c * (CHUNK2 / 4);
    const size_t wbase = (size_t)(kg * RPB) * (FC_IN_N / 4) + (size_t)c * (CHUNK2 / 4);
    const floatx4* wp0 = reinterpret_cast<const floatx4*>(fcw) + wbase;
    const floatx4* wp1 = wp0 + (FC_IN_N / 4);
    const floatx4* wp2 = wp1 + (FC_IN_N / 4);
    const floatx4* wp3 = wp2 + (FC_IN_N / 4);

    float a0 = 0.f, a1 = 0.f, a2 = 0.f, a3 = 0.f;
    #pragma unroll 5
    for (int i = 0; i < CHUNK2 / 4 / 256; ++i) {   // 65 iterations
        const int idx = i * 256 + tid;
        floatx4 w0 = __builtin_nontemporal_load(wp0 + idx);
        floatx4 w1 = __builtin_nontemporal_load(wp1 + idx);
        floatx4 w2 = __builtin_nontemporal_load(wp2 + idx);
        floatx4 w3 = __builtin_nontemporal_load(wp3 + idx);
        float4 hv = hp[idx];
        a0 += w0.x * hv.x + w0.y * hv.y + w0.z * hv.z + w0.w * hv.w;
        a1 += w1.x * hv.x + w1.y * hv.y + w1.z * hv.z + w1.w * hv.w;
        a2 += w2.x * hv.x + w2.y * hv.y + w2.z * hv.z + w2.w * hv.w;
        a3 += w3.x * hv.x + w3.y * hv.y + w3.z * hv.z + w3.w * hv.w;
    }

    #pragma unroll
    for (int m = 32; m >= 1; m >>= 1) {
        a0 += __shfl_xor(a0, m);
        a1 += __shfl_xor(a1, m);
        a2 += __shfl_xor(a2, m);
        a3 += __shfl_xor(a3, m);
    }
    __shared__ float red[4][RPB];
    if ((tid & 63) == 0) {
        const int wv = tid >> 6;
        red[wv][0] = a0; red[wv][1] = a1; red[wv][2] = a2; red[wv][3] = a3;
    }
    __syncthreads();
    if (tid < RPB) {
        // partials[swz*RPB + j] == partials[c*64 + kg*4 + j] == partials[c*64 + k]
        partials[(size_t)swz * RPB + tid] =
            red[0][tid] + red[1][tid] + red[2][tid] + red[3][tid];
    }
}

// out[k] = sigmoid(fc_b[k] + sum_c partials[c*64 + k])
__global__ __launch_bounds__(256) void k_fin(const float* __restrict__ partials,
                                             const float* __restrict__ fcb,
                                             float* __restrict__ out) {
    const int tid = threadIdx.x;
    const int k = tid & 63, g = tid >> 6;
    float s = 0.f;
    for (int b = g; b < NCH; b += 4) s += partials[(size_t)b * 64 + k];
    __shared__ float red[4][64];
    red[g][k] = s;
    __syncthreads();
    if (tid < 64) {
        float t = red[0][tid] + red[1][tid] + red[2][tid] + red[3][tid] + fcb[tid];
        out[tid] = 1.0f / (1.0f + expf(-t));
    }
}

extern "C" void kernel_launch(void* const* d_in, const int* in_sizes, int n_in,
                              void* d_out, int out_size, void* d_ws, size_t ws_size,
                              hipStream_t stream) {
    const int*   inputs = (const int*)  d_in[0];
    const float* rf     = (const float*)d_in[1];
    const float* embed  = (const float*)d_in[2];
    const float* rel    = (const float*)d_in[3];
    const float* dise   = (const float*)d_in[4];
    const float* fcw    = (const float*)d_in[5];
    const float* fcb    = (const float*)d_in[6];
    float* out = (float*)d_out;

    // ws layout (floats): h[FC_IN] | partials[NCH*64] | DE[64*4096] | DR[64*8] | dsc[64] | xinv[32768]
    float* ws = (float*)d_ws;
    float* h        = ws;
    float* partials = h + FC_IN_N;
    float* DE       = partials + NCH * 64;
    float* DR       = DE + (size_t)DD_N * S_N;
    float* dsc_g    = DR + DD_N * REL_N;
    float* xinv     = dsc_g + 64;

    hipLaunchKernelGGL(k_pre1, dim3(S_N / 64), dim3(256), 0, stream, dise, embed, rel, DE, DR, dsc_g);
    hipLaunchKernelGGL(k_pre0, dim3(S_N / 64), dim3(256), 0, stream, inputs, embed, rel, xinv);
    hipLaunchKernelGGL(k_kg2,  dim3(DD_N * 4), dim3(256), 0, stream, rf, DE, DR, dsc_g, xinv, h);
    hipLaunchKernelGGL(k_mv,   dim3(NBLK3),    dim3(256), 0, stream, fcw, h, partials);
    hipLaunchKernelGGL(k_fin,  dim3(1),        dim3(256), 0, stream, partials, fcb, out);
}

// Round 7
// 112.068 us; speedup vs baseline: 2.3897x; 1.0523x over previous
//
#include <hip/hip_runtime.h>
#include <math.h>

namespace {
constexpr int S_N   = 4096;
constexpr int D_N   = 128;
constexpr int DD_N  = 64;
constexpr int REL_N = 8;
constexpr int R_N   = 512;
constexpr int NTOT  = S_N * REL_N;                        // 32768
constexpr int ROWLEN = R_N + NTOT;                        // 33280
constexpr long long FC_IN_N = (long long)DD_N * ROWLEN;   // 2,129,920
constexpr int NCH   = 32;                                 // col chunks per w-row
constexpr int CHUNK2 = (int)(FC_IN_N / NCH);              // 66,560 floats = 260 KB = exactly 2 h-rows
constexpr int NF4   = CHUNK2 / 4;                         // 16,640 float4 per chunk
constexpr int RPB   = 8;                                  // output rows per k_mv block
constexpr int KG_N  = DD_N / RPB;                         // 8 k-groups
constexpr int NBLK3 = NCH * KG_N;                         // 256 blocks (1/CU, mult of 8)
constexpr int SEP   = 132;                                // padded LDS row stride (floats)
typedef float floatx4 __attribute__((ext_vector_type(4)));

__device__ __forceinline__ float dot4(const float4& a, const float4& b) {
    return a.x*b.x + a.y*b.y + a.z*b.z + a.w*b.w;
}
}

// Fused pre-kernel, 256 blocks x 16 symptoms each:
//   DE[dd][s] = dise[dd].embed[s]
//   xinv[s*8+r] = mask[s]&&sq>0 ? rsqrt(||e_s||^2 + 2 e_s.rel_r + ||rel_r||^2) : 0
//   block 0 also: dsc[dd]=1/||dise[dd]||, DR[dd][r]=dise[dd].rel[r]
__global__ __launch_bounds__(256) void k_pre(const int* __restrict__ inputs,
                                             const float* __restrict__ dise,
                                             const float* __restrict__ embed,
                                             const float* __restrict__ rel,
                                             float* __restrict__ DE,
                                             float* __restrict__ DR,
                                             float* __restrict__ dsc_g,
                                             float* __restrict__ xinv) {
    __shared__ float sd[DD_N * 129];                  // dise, pad 129 (2-way = free)
    __shared__ __align__(16) float se[16 * SEP];      // embed tile, stride 132 (conflict-free groups)
    __shared__ __align__(16) float sr[REL_N * SEP];   // rel, stride 132
    __shared__ float rr[REL_N];
    const int tid  = threadIdx.x;
    const int lane = tid & 63;
    const int wave = tid >> 6;
    const int s0   = blockIdx.x * 16;

    for (int i = tid; i < DD_N * D_N; i += 256)
        sd[(i >> 7) * 129 + (i & 127)] = dise[i];
    for (int i = tid; i < 16 * 32; i += 256) {        // 512 float4s of embed tile
        const int row = i >> 5, col = i & 31;
        *reinterpret_cast<float4*>(&se[row * SEP + col * 4]) =
            reinterpret_cast<const float4*>(embed + (size_t)s0 * D_N)[i];
    }
    if (tid < REL_N * 32) {                           // 256 float4s of rel
        const int row = tid >> 5, col = tid & 31;
        *reinterpret_cast<float4*>(&sr[row * SEP + col * 4]) =
            reinterpret_cast<const float4*>(rel)[tid];
    }
    __syncthreads();

    if (tid < REL_N) {
        float a = 0.f;
        for (int e = 0; e < D_N; ++e) { float v = sr[tid * SEP + e]; a += v * v; }
        rr[tid] = a;
    }

    float dw[D_N];
    float dsq = 0.f;
    #pragma unroll
    for (int e = 0; e < D_N; ++e) {
        dw[e] = sd[lane * 129 + e];
        dsq += dw[e] * dw[e];
    }
    const float dsc = rsqrtf(dsq);

    if (blockIdx.x == 0) {
        if (wave == 0) dsc_g[lane] = dsc;
        #pragma unroll
        for (int rr2 = 0; rr2 < 2; ++rr2) {
            const int r = wave * 2 + rr2;
            float a = 0.f;
            #pragma unroll
            for (int e = 0; e < D_N; ++e) a += dw[e] * sr[r * SEP + e];
            DR[lane * REL_N + r] = a;
        }
    }

    // DE: wave handles s-locals [wave*4, wave*4+4); se reads broadcast within 64-lane groups
    {
        float4 o;
        float* op = reinterpret_cast<float*>(&o);
        #pragma unroll
        for (int jj = 0; jj < 4; ++jj) {
            const int nl = wave * 4 + jj;
            const float4* xr = reinterpret_cast<const float4*>(&se[nl * SEP]);
            float a0 = 0.f, a1 = 0.f, a2 = 0.f, a3 = 0.f;
            #pragma unroll
            for (int i = 0; i < 32; i += 4) {
                float4 x0 = xr[i], x1 = xr[i + 1], x2 = xr[i + 2], x3 = xr[i + 3];
                a0 += dw[4*i+ 0]*x0.x + dw[4*i+ 1]*x0.y + dw[4*i+ 2]*x0.z + dw[4*i+ 3]*x0.w;
                a1 += dw[4*i+ 4]*x1.x + dw[4*i+ 5]*x1.y + dw[4*i+ 6]*x1.z + dw[4*i+ 7]*x1.w;
                a2 += dw[4*i+ 8]*x2.x + dw[4*i+ 9]*x2.y + dw[4*i+10]*x2.z + dw[4*i+11]*x2.w;
                a3 += dw[4*i+12]*x3.x + dw[4*i+13]*x3.y + dw[4*i+14]*x3.z + dw[4*i+15]*x3.w;
            }
            op[jj] = a0 + a1 + a2 + a3;
        }
        *reinterpret_cast<float4*>(DE + (size_t)lane * S_N + s0 + wave * 4) = o;
    }

    __syncthreads();   // rr ready

    // xinv: 128 threads, one (s-local, r) pair each
    if (tid < 128) {
        const int sl = tid >> 3, r = tid & 7;
        const float4* ev4 = reinterpret_cast<const float4*>(&se[sl * SEP]);
        const float4* rv4 = reinterpret_cast<const float4*>(&sr[r * SEP]);
        float ee = 0.f, er = 0.f;
        #pragma unroll
        for (int i = 0; i < 32; ++i) {
            float4 ev = ev4[i], rv = rv4[i];
            ee += dot4(ev, ev);
            er += dot4(ev, rv);
        }
        const float sq = ee + 2.f * er + rr[r];
        const bool m = (inputs[s0 + sl] != 0);
        xinv[(size_t)(s0 + sl) * REL_N + r] = (m && sq > 0.f) ? rsqrtf(sq) : 0.f;
    }
}

// h kg block: h[dd*ROWLEN+512+n] = dsc[dd]*xinv[n]*(DE[dd][s]+DR[dd][r]); q==0 also copies rules row
__global__ __launch_bounds__(256) void k_kg2(const float* __restrict__ rf,
                                             const float* __restrict__ DE,
                                             const float* __restrict__ DR,
                                             const float* __restrict__ dsc_g,
                                             const float* __restrict__ xinv,
                                             float* __restrict__ h) {
    __shared__ __align__(16) float sx[8192];
    __shared__ float sD[1024];
    const int tid = threadIdx.x;
    const int dd  = blockIdx.x >> 2;
    const int q   = blockIdx.x & 3;
    const int n0  = q * 8192;
    const int s0  = q * 1024;

    for (int i = tid; i < 2048; i += 256)
        reinterpret_cast<float4*>(sx)[i] = reinterpret_cast<const float4*>(xinv + n0)[i];
    if (tid < 256)
        reinterpret_cast<float4*>(sD)[tid] =
            reinterpret_cast<const float4*>(DE + (size_t)dd * S_N + s0)[tid];
    const float dsc = dsc_g[dd];
    const float4 drlo = reinterpret_cast<const float4*>(DR + dd * REL_N)[0];
    const float4 drhi = reinterpret_cast<const float4*>(DR + dd * REL_N)[1];
    const float4 drv = (tid & 1) ? drhi : drlo;   // r-base is 4*(tid&1), thread-constant
    __syncthreads();

    float* hb = h + (size_t)dd * ROWLEN + R_N + n0;
    #pragma unroll
    for (int i = 0; i < 8; ++i) {
        const int f4i = i * 256 + tid;            // float4 index, lanes consecutive
        const int ln  = f4i * 4;
        const float de = sD[f4i >> 1];            // s-local = ln>>3
        float4 xv = reinterpret_cast<const float4*>(sx)[f4i];
        float4 o;
        o.x = dsc * xv.x * (de + drv.x);
        o.y = dsc * xv.y * (de + drv.y);
        o.z = dsc * xv.z * (de + drv.z);
        o.w = dsc * xv.w * (de + drv.w);
        *reinterpret_cast<float4*>(hb + ln) = o;
    }
    if (q == 0 && tid < 128)
        reinterpret_cast<float4*>(h + (size_t)dd * ROWLEN)[tid] =
            reinterpret_cast<const float4*>(rf + (size_t)dd * R_N)[tid];
}

// block (kg, c) after XCD swizzle: out rows kg*8..kg*8+7, cols [c*66560, (c+1)*66560).
// 8 contiguous 260 KB nontemporal w-streams per block; h chunk read by only 8 blocks,
// all on one XCD (L2-served). 256 blocks = 1/CU, 8 waves/CU.
__global__ __launch_bounds__(512, 1) void k_mv(const float* __restrict__ fcw,
                                               const float* __restrict__ h,
                                               float* __restrict__ partials) {
    const int tid = threadIdx.x;
    // bijective XCD swizzle (256 % 8 == 0): chunk c's 8 blocks cluster on one XCD
    const int swz = (blockIdx.x & 7) * (NBLK3 / 8) + (blockIdx.x >> 3);
    const int c  = swz >> 3;      // 0..31
    const int kg = swz & 7;       // 0..7

    const float4* hp = reinterpret_cast<const float4*>(h) + (size_t)c * NF4;
    const floatx4* wp = reinterpret_cast<const floatx4*>(fcw)
                        + (size_t)(kg * RPB) * (FC_IN_N / 4) + (size_t)c * NF4;

    float acc[RPB];
    #pragma unroll
    for (int j = 0; j < RPB; ++j) acc[j] = 0.f;

    #pragma unroll 2
    for (int i = 0; i < 32; ++i) {                 // 32 full iterations of 512 f4
        const int idx = i * 512 + tid;
        float4 hv = hp[idx];
        #pragma unroll
        for (int j = 0; j < RPB; ++j) {
            floatx4 w = __builtin_nontemporal_load(wp + (size_t)j * (FC_IN_N / 4) + idx);
            acc[j] += w.x * hv.x + w.y * hv.y + w.z * hv.z + w.w * hv.w;
        }
    }
    if (tid < 256) {                               // tail: 16640 - 32*512 = 256 f4
        const int idx = 32 * 512 + tid;
        float4 hv = hp[idx];
        #pragma unroll
        for (int j = 0; j < RPB; ++j) {
            floatx4 w = __builtin_nontemporal_load(wp + (size_t)j * (FC_IN_N / 4) + idx);
            acc[j] += w.x * hv.x + w.y * hv.y + w.z * hv.z + w.w * hv.w;
        }
    }

    #pragma unroll
    for (int m = 32; m >= 1; m >>= 1) {
        #pragma unroll
        for (int j = 0; j < RPB; ++j) acc[j] += __shfl_xor(acc[j], m);
    }
    __shared__ float red[8][RPB];
    if ((tid & 63) == 0) {
        const int wv = tid >> 6;
        #pragma unroll
        for (int j = 0; j < RPB; ++j) red[wv][j] = acc[j];
    }
    __syncthreads();
    if (tid < RPB) {
        float s = 0.f;
        #pragma unroll
        for (int wv = 0; wv < 8; ++wv) s += red[wv][tid];
        // partials[swz*RPB + j] == partials[c*64 + kg*8 + j]
        partials[(size_t)swz * RPB + tid] = s;
    }
}

// out[k] = sigmoid(fc_b[k] + sum_c partials[c*64 + k])
__global__ __launch_bounds__(256) void k_fin(const float* __restrict__ partials,
                                             const float* __restrict__ fcb,
                                             float* __restrict__ out) {
    const int tid = threadIdx.x;
    const int k = tid & 63, g = tid >> 6;
    float s = 0.f;
    for (int b = g; b < NCH; b += 4) s += partials[(size_t)b * 64 + k];
    __shared__ float red[4][64];
    red[g][k] = s;
    __syncthreads();
    if (tid < 64) {
        float t = red[0][tid] + red[1][tid] + red[2][tid] + red[3][tid] + fcb[tid];
        out[tid] = 1.0f / (1.0f + expf(-t));
    }
}

extern "C" void kernel_launch(void* const* d_in, const int* in_sizes, int n_in,
                              void* d_out, int out_size, void* d_ws, size_t ws_size,
                              hipStream_t stream) {
    const int*   inputs = (const int*)  d_in[0];
    const float* rf     = (const float*)d_in[1];
    const float* embed  = (const float*)d_in[2];
    const float* rel    = (const float*)d_in[3];
    const float* dise   = (const float*)d_in[4];
    const float* fcw    = (const float*)d_in[5];
    const float* fcb    = (const float*)d_in[6];
    float* out = (float*)d_out;

    // ws layout (floats): h[FC_IN] | partials[NCH*64] | DE[64*4096] | DR[64*8] | dsc[64] | xinv[32768]
    float* ws = (float*)d_ws;
    float* h        = ws;
    float* partials = h + FC_IN_N;
    float* DE       = partials + NCH * 64;
    float* DR       = DE + (size_t)DD_N * S_N;
    float* dsc_g    = DR + DD_N * REL_N;
    float* xinv     = dsc_g + 64;

    hipLaunchKernelGGL(k_pre,  dim3(S_N / 16), dim3(256), 0, stream,
                       inputs, dise, embed, rel, DE, DR, dsc_g, xinv);
    hipLaunchKernelGGL(k_kg2,  dim3(DD_N * 4), dim3(256), 0, stream, rf, DE, DR, dsc_g, xinv, h);
    hipLaunchKernelGGL(k_mv,   dim3(NBLK3),    dim3(512), 0, stream, fcw, h, partials);
    hipLaunchKernelGGL(k_fin,  dim3(1),        dim3(256), 0, stream, partials, fcb, out);
}